// Round 4
// baseline (388.512 us; speedup 1.0000x reference)
//
#include <hip/hip_runtime.h>

typedef unsigned short u16;
typedef _Float16 f16x8 __attribute__((ext_vector_type(8)));
typedef float f32x16 __attribute__((ext_vector_type(16)));
typedef unsigned int u32x4 __attribute__((ext_vector_type(4)));

#define LOG2E 1.44269504088896340736f

static __device__ __forceinline__ u16 f2h(float f){
  union { _Float16 h; u16 u; } v; v.h = (_Float16)f; return v.u;
}
static __device__ __forceinline__ unsigned pk2h(float lo, float hi){
  unsigned r; asm("v_cvt_pkrtz_f16_f32 %0, %1, %2" : "=v"(r) : "v"(lo), "v"(hi)); return r;
}

// B=8, C=512, N=4096, MID=64
// ---------------- kernel 0: x[b][c][n] f32 -> xt[b][n][c] f16 ----------------
__global__ __launch_bounds__(256) void k_tr(const float* __restrict__ x, u16* __restrict__ xt){
  int bx = blockIdx.x;
  int nb = bx & 63, cb = (bx >> 6) & 7, b = bx >> 9;
  __shared__ u16 lt[64 * 68];  // [c][n], stride 68 keeps 8B align for writes
  int t = threadIdx.x;
  int cl = t >> 4, n0 = (t & 15) * 4;
  const float* xp = x + ((size_t)(b * 512 + cb * 64)) * 4096 + nb * 64;
#pragma unroll
  for (int i = 0; i < 4; ++i) {
    int c = cl + i * 16;
    float4 v = *(const float4*)(xp + (size_t)c * 4096 + n0);
    u16* d = &lt[c * 68 + n0];
    d[0] = f2h(v.x); d[1] = f2h(v.y); d[2] = f2h(v.z); d[3] = f2h(v.w);
  }
  __syncthreads();
  u16* xo = xt + ((size_t)(b * 4096 + nb * 64)) * 512 + cb * 64;
#pragma unroll
  for (int i = 0; i < 2; ++i) {
    int s = t + i * 256;
    int n = s >> 3, ch = s & 7;
    u32x4 o;
#pragma unroll
    for (int j = 0; j < 4; ++j) {
      u16 a = lt[(ch * 8 + 2 * j) * 68 + n];
      u16 bb = lt[(ch * 8 + 2 * j + 1) * 68 + n];
      o[j] = (unsigned)a | ((unsigned)bb << 16);
    }
    *(u32x4*)(xo + (size_t)n * 512 + ch * 8) = o;
  }
}

// ------------- kernel 1: qk[b][n][0..64)=Q=Xt*(LOG2E*Wb)^T, [64..128)=K=Xt*Wc^T -------------
__global__ __launch_bounds__(512) void k_pqk(const u16* __restrict__ xt, const float* __restrict__ wb,
                                             const float* __restrict__ wc, u16* __restrict__ qk){
  int bx = blockIdx.x;
  int nb = bx & 31, b = bx >> 5;
  __shared__ u16 lx[128 * 64];  // [n][c] swizzled
  __shared__ u16 lw[128 * 64];  // [m][c] swizzled (rows 0-63 Wb*log2e, 64-127 Wc)
  int t = threadIdx.x, w = t >> 6, l = t & 63, hi = l >> 5, ln = l & 31;
  int wr = w >> 1, wcol = w & 1;
  f32x16 acc[2] = {};
  for (int kt = 0; kt < 8; ++kt) {
    int c0 = kt * 64;
#pragma unroll
    for (int i = 0; i < 2; ++i) {
      int s = t + i * 512; int row = s >> 3, ch = s & 7;
      u32x4 v = *(const u32x4*)(xt + ((size_t)(b * 4096 + nb * 128 + row)) * 512 + c0 + ch * 8);
      *(u32x4*)((char*)lx + ((row * 128 + ch * 16) ^ ((row & 7) << 4))) = v;
    }
#pragma unroll
    for (int i = 0; i < 4; ++i) {
      int s = t + i * 512; int row = s >> 4, c4 = s & 15;
      const float* src = (row < 64) ? (wb + (size_t)row * 512 + c0 + c4 * 4)
                                    : (wc + (size_t)(row - 64) * 512 + c0 + c4 * 4);
      float4 v = *(const float4*)src;
      float sc = (row < 64) ? LOG2E : 1.0f;  // fold exp2-domain scale into Wb
      unsigned lo = (unsigned)f2h(v.x * sc) | ((unsigned)f2h(v.y * sc) << 16);
      unsigned h2 = (unsigned)f2h(v.z * sc) | ((unsigned)f2h(v.w * sc) << 16);
      unsigned long long qv = ((unsigned long long)h2 << 32) | lo;
      *(unsigned long long*)((char*)lw + ((row * 128 + c4 * 8) ^ ((row & 7) << 4))) = qv;
    }
    __syncthreads();
#pragma unroll
    for (int cc = 0; cc < 4; ++cc) {
      int ra = wr * 32 + ln;
      f16x8 a = *(const f16x8*)((char*)lx + ((ra * 128 + cc * 32 + hi * 16) ^ ((ra & 7) << 4)));
#pragma unroll
      for (int mt = 0; mt < 2; ++mt) {
        int rb = wcol * 64 + mt * 32 + ln;
        f16x8 bb = *(const f16x8*)((char*)lw + ((rb * 128 + cc * 32 + hi * 16) ^ ((rb & 7) << 4)));
        acc[mt] = __builtin_amdgcn_mfma_f32_32x32x16_f16(a, bb, acc[mt], 0, 0, 0);
      }
    }
    __syncthreads();
  }
#pragma unroll
  for (int mt = 0; mt < 2; ++mt)
#pragma unroll
    for (int r = 0; r < 16; ++r) {
      int n = wr * 32 + (r & 3) + 8 * (r >> 2) + 4 * hi;
      int m = wcol * 64 + mt * 32 + ln;
      qk[((size_t)(b * 4096 + nb * 128 + n)) * 128 + m] = f2h(acc[mt][r]);
    }
}

// ------------- kernel 2: vt[b][o][n] = (Wd * Xt^T), i.e. V transposed -------------
__global__ __launch_bounds__(512) void k_pv(const u16* __restrict__ xt, const float* __restrict__ wd,
                                            u16* __restrict__ vt){
  int bx = blockIdx.x;
  int nb = bx & 31, ob = (bx >> 5) & 3, b = bx >> 7;
  __shared__ u16 lx[128 * 64];  // [n][c] swizzled
  __shared__ u16 lw[128 * 64];  // [o][c] swizzled
  int t = threadIdx.x, w = t >> 6, l = t & 63, hi = l >> 5, ln = l & 31;
  int wr = w >> 2, wn = w & 3;
  f32x16 acc[2] = {};
  for (int kt = 0; kt < 8; ++kt) {
    int c0 = kt * 64;
#pragma unroll
    for (int i = 0; i < 2; ++i) {
      int s = t + i * 512; int row = s >> 3, ch = s & 7;
      u32x4 v = *(const u32x4*)(xt + ((size_t)(b * 4096 + nb * 128 + row)) * 512 + c0 + ch * 8);
      *(u32x4*)((char*)lx + ((row * 128 + ch * 16) ^ ((row & 7) << 4))) = v;
    }
#pragma unroll
    for (int i = 0; i < 4; ++i) {
      int s = t + i * 512; int row = s >> 4, c4 = s & 15;
      const float* src = wd + (size_t)(ob * 128 + row) * 512 + c0 + c4 * 4;
      float4 v = *(const float4*)src;
      unsigned lo = (unsigned)f2h(v.x) | ((unsigned)f2h(v.y) << 16);
      unsigned h2 = (unsigned)f2h(v.z) | ((unsigned)f2h(v.w) << 16);
      unsigned long long qv = ((unsigned long long)h2 << 32) | lo;
      *(unsigned long long*)((char*)lw + ((row * 128 + c4 * 8) ^ ((row & 7) << 4))) = qv;
    }
    __syncthreads();
#pragma unroll
    for (int cc = 0; cc < 4; ++cc) {
      int rb = wn * 32 + ln;
      f16x8 bb = *(const f16x8*)((char*)lx + ((rb * 128 + cc * 32 + hi * 16) ^ ((rb & 7) << 4)));
#pragma unroll
      for (int ot = 0; ot < 2; ++ot) {
        int ra = wr * 64 + ot * 32 + ln;
        f16x8 a = *(const f16x8*)((char*)lw + ((ra * 128 + cc * 32 + hi * 16) ^ ((ra & 7) << 4)));
        acc[ot] = __builtin_amdgcn_mfma_f32_32x32x16_f16(a, bb, acc[ot], 0, 0, 0);
      }
    }
    __syncthreads();
  }
#pragma unroll
  for (int ot = 0; ot < 2; ++ot)
#pragma unroll
    for (int r = 0; r < 16; ++r) {
      int o = ob * 128 + wr * 64 + ot * 32 + (r & 3) + 8 * (r >> 2) + 4 * hi;
      int n = nb * 128 + wn * 32 + ln;
      vt[((size_t)(b * 512 + o)) * 4096 + n] = f2h(acc[ot][r]);
    }
}

// ------------- kernel 3: flash attention + residual epilogue -------------
// grid 512: combo=bx&31 (b=combo>>2, oc=combo&3), qt=bx>>5
// block: 8 waves x 32 q-rows (q-tile 256); o-chunk 128; KV tile 64.
// Swapped-QK layout: lane (hi,ln) holds SCORES for q=ln; PV accumulator rows are
// q=crow(r,hi)=(r&3)+8*(r>>2)+4*hi -> per-row rescale distributed via per-wave LDS rsc[32].
__global__ __launch_bounds__(512, 2) void k_attn(const u16* __restrict__ qk, const u16* __restrict__ vt,
                                                 const float* __restrict__ x, const float* __restrict__ gamma,
                                                 float* __restrict__ out){
  __shared__ char smem[33792];
  u16* lk = (u16*)smem;             // [64 k][64 m], xor-swizzled
  u16* lv = (u16*)(smem + 8192);    // [128 o][64 k], xor-swizzled
  int bx = blockIdx.x;
  int combo = bx & 31, qt = bx >> 5;
  int b = combo >> 2, oc = combo & 3;
  int obase = oc * 128;
  int t = threadIdx.x, w = t >> 6, l = t & 63, hi = l >> 5, ln = l & 31;
  float* rsc = (float*)(smem + 24576) + w * 32;  // per-wave row-scale broadcast
  int q = qt * 256 + w * 32 + ln;
  size_t b4096 = (size_t)b * 4096;
  // Q B-fragments (already scaled by log2(e) in k_pqk)
  f16x8 qf[4];
  {
    const u16* qrow = qk + (b4096 + q) * 128;
#pragma unroll
    for (int ch = 0; ch < 4; ++ch) qf[ch] = *(const f16x8*)(qrow + ch * 16 + hi * 8);
  }
  f32x16 acc[4] = {};
  float m_run = -3.0e38f, l_half = 0.0f;
  // staging slot assignment
  int rowK = t >> 3, chK = t & 7;
  u32x4 kreg, vreg0, vreg1;
  {
    kreg  = *(const u32x4*)(qk + (b4096 + rowK) * 128 + 64 + chK * 8);
    vreg0 = *(const u32x4*)(vt + ((size_t)(b * 512 + obase + rowK)) * 4096 + chK * 8);
    vreg1 = *(const u32x4*)(vt + ((size_t)(b * 512 + obase + 64 + rowK)) * 4096 + chK * 8);
  }
  for (int kt = 0; kt < 64; ++kt) {
    *(u32x4*)((char*)lk + ((rowK * 128 + chK * 16) ^ ((rowK & 7) << 4))) = kreg;
    *(u32x4*)((char*)lv + ((rowK * 128 + chK * 16) ^ ((rowK & 7) << 4))) = vreg0;
    {
      int r2 = 64 + rowK;
      *(u32x4*)((char*)lv + ((r2 * 128 + chK * 16) ^ ((r2 & 7) << 4))) = vreg1;
    }
    __syncthreads();
    if (kt < 63) {  // prefetch next tile into regs (hides under compute)
      int k0 = (kt + 1) * 64;
      kreg  = *(const u32x4*)(qk + (b4096 + k0 + rowK) * 128 + 64 + chK * 8);
      vreg0 = *(const u32x4*)(vt + ((size_t)(b * 512 + obase + rowK)) * 4096 + k0 + chK * 8);
      vreg1 = *(const u32x4*)(vt + ((size_t)(b * 512 + obase + 64 + rowK)) * 4096 + k0 + chK * 8);
    }
    // S^T = K * Q^T : lane holds 32 scores for its q-row (split with lane^32)
    f32x16 s0 = {}, s1 = {};
#pragma unroll
    for (int cc = 0; cc < 4; ++cc) {
      int r0 = ln, r1 = 32 + ln;
      f16x8 k0 = *(const f16x8*)((char*)lk + ((r0 * 128 + cc * 32 + hi * 16) ^ ((r0 & 7) << 4)));
      f16x8 k1 = *(const f16x8*)((char*)lk + ((r1 * 128 + cc * 32 + hi * 16) ^ ((r1 & 7) << 4)));
      s0 = __builtin_amdgcn_mfma_f32_32x32x16_f16(k0, qf[cc], s0, 0, 0, 0);
      s1 = __builtin_amdgcn_mfma_f32_32x32x16_f16(k1, qf[cc], s1, 0, 0, 0);
    }
    // online softmax (log2 domain), per-lane state tracks q=ln
    float pm = s0[0];
#pragma unroll
    for (int r = 1; r < 16; ++r) pm = fmaxf(pm, s0[r]);
#pragma unroll
    for (int r = 0; r < 16; ++r) pm = fmaxf(pm, s1[r]);
    pm = fmaxf(pm, __shfl_xor(pm, 32));
    float mn = fmaxf(m_run, pm);
    float sc = exp2f(m_run - mn);
    m_run = mn;
    float ls = 0.0f;
#pragma unroll
    for (int r = 0; r < 16; ++r) { s0[r] = exp2f(s0[r] - mn); ls += s0[r]; }
#pragma unroll
    for (int r = 0; r < 16; ++r) { s1[r] = exp2f(s1[r] - mn); ls += s1[r]; }
    l_half = l_half * sc + ls;
    // distribute per-row scale: acc row q' = crow(r,hi) needs sc of lane ln=q'
    if (!hi) rsc[ln] = sc;
    __builtin_amdgcn_sched_barrier(0);
    float scr[16];
#pragma unroll
    for (int g = 0; g < 4; ++g) {
      float4 s4 = *(const float4*)(rsc + g * 8 + hi * 4);
      scr[g * 4 + 0] = s4.x; scr[g * 4 + 1] = s4.y; scr[g * 4 + 2] = s4.z; scr[g * 4 + 3] = s4.w;
    }
    __builtin_amdgcn_sched_barrier(0);
#pragma unroll
    for (int ot = 0; ot < 4; ++ot)
#pragma unroll
      for (int r = 0; r < 16; ++r) acc[ot][r] *= scr[r];
    // pack P->f16 A-fragments (cvt_pkrtz + lane^32 exchange), then PV
#pragma unroll
    for (int kb = 0; kb < 2; ++kb) {
      f32x16& sv = kb ? s1 : s0;
      unsigned cp[8], sx[8];
#pragma unroll
      for (int i = 0; i < 8; ++i) cp[i] = pk2h(sv[2 * i], sv[2 * i + 1]);
#pragma unroll
      for (int i = 0; i < 8; ++i) sx[i] = __shfl_xor(cp[i], 32);
      union { unsigned u[4]; f16x8 v; } f0, f1;
      if (hi) {
        f0.u[0] = sx[2]; f0.u[1] = sx[3]; f0.u[2] = cp[2]; f0.u[3] = cp[3];
        f1.u[0] = sx[6]; f1.u[1] = sx[7]; f1.u[2] = cp[6]; f1.u[3] = cp[7];
      } else {
        f0.u[0] = cp[0]; f0.u[1] = cp[1]; f0.u[2] = sx[0]; f0.u[3] = sx[1];
        f1.u[0] = cp[4]; f1.u[1] = cp[5]; f1.u[2] = sx[4]; f1.u[3] = sx[5];
      }
#pragma unroll
      for (int c2 = 0; c2 < 2; ++c2) {
        f16x8 pa = c2 ? f1.v : f0.v;
        int kc = kb * 2 + c2;
#pragma unroll
        for (int ot = 0; ot < 4; ++ot) {
          int rv = ot * 32 + ln;
          f16x8 vb = *(const f16x8*)((char*)lv + ((rv * 128 + kc * 32 + hi * 16) ^ ((rv & 7) << 4)));
          acc[ot] = __builtin_amdgcn_mfma_f32_32x32x16_f16(pa, vb, acc[ot], 0, 0, 0);
        }
      }
    }
    __syncthreads();
  }
  // epilogue: normalize, transpose 32x32 tiles via LDS, coalesced residual+store
  float lt2 = l_half + __shfl_xor(l_half, 32);
  float g = gamma[0];
  float scale = g / lt2;
  __syncthreads();
  float* tb = (float*)smem + w * 1056;  // per-wave 32x33 f32
#pragma unroll
  for (int ot = 0; ot < 4; ++ot) {
#pragma unroll
    for (int r = 0; r < 16; ++r) {
      int qr = (r & 3) + 8 * (r >> 2) + 4 * hi;
      tb[ln * 33 + qr] = acc[ot][r];
    }
#pragma unroll
    for (int it = 0; it < 16; ++it) {
      int orow = it * 2 + hi;
      float v = tb[orow * 33 + ln];
      size_t gi = (((size_t)(b * 512 + obase + ot * 32 + orow)) << 12) + (size_t)(qt * 256 + w * 32 + ln);
      out[gi] = scale * v + x[gi];
    }
  }
}

extern "C" void kernel_launch(void* const* d_in, const int* in_sizes, int n_in,
                              void* d_out, int out_size, void* d_ws, size_t ws_size,
                              hipStream_t stream) {
  (void)in_sizes; (void)n_in; (void)out_size; (void)ws_size;
  const float* x     = (const float*)d_in[0];
  const float* wb    = (const float*)d_in[1];
  const float* wc    = (const float*)d_in[2];
  const float* wd    = (const float*)d_in[3];
  const float* gamma = (const float*)d_in[4];
  float* out = (float*)d_out;
  char* ws = (char*)d_ws;
  u16* xt  = (u16*)ws;                    // 32 MB: Xt f16 [B][N][C]
  u16* qkb = (u16*)(ws + 33554432);       //  8 MB: [B][N][Q(64)|K(64)]
  u16* vtb = (u16*)(ws + 41943040);       // 32 MB: V^T f16 [B][C][N]
  k_tr  <<<dim3(4096), dim3(256), 0, stream>>>(x, xt);
  k_pqk <<<dim3(256),  dim3(512), 0, stream>>>(xt, wb, wc, qkb);
  k_pv  <<<dim3(1024), dim3(512), 0, stream>>>(xt, wd, vtb);
  k_attn<<<dim3(512),  dim3(512), 0, stream>>>(qkb, vtb, x, gamma, out);
}